// Round 4
// baseline (388.872 us; speedup 1.0000x reference)
//
#include <hip/hip_runtime.h>

#define PS 32
#define NPIX (PS * PS)
#define NB 36
#define WPB 4      // waves (patches) per block
#define RCOL 32    // histogram replica columns per wave (kills same-address atomics)
#define FCAP 64    // deferred-fixup list capacity per wave

// ---------------------------------------------------------------------------
// Init kernel: gk10[p] = float32(10 * CircularGaussKernel(32)) computed in f64,
// replicating numpy linspace + exp + normalize semantics, then cast to f32.
// ---------------------------------------------------------------------------
__global__ __launch_bounds__(256) void gk_init_kernel(float* __restrict__ gk10) {
    __shared__ double red[256];
    const int tid = threadIdx.x;
    const double delta = 32.0 / 31.0;       // numpy linspace step, f64
    const double sigma2 = 0.9 * 256.0;      // 0.9 * half^2, f64

    double kv[4];
    double s = 0.0;
#pragma unroll
    for (int j = 0; j < 4; ++j) {
        int p = tid * 4 + j;
        int r = p >> 5, c = p & 31;
        double xr = (r == 31) ? 16.0 : ((double)r * delta + (-16.0));
        double xc = (c == 31) ? 16.0 : ((double)c * delta + (-16.0));
        double d2 = xc * xc + xr * xr;
        kv[j] = exp(-d2 / sigma2);
        s += kv[j];
    }
    red[tid] = s;
    __syncthreads();
    for (int off = 128; off > 0; off >>= 1) {
        if (tid < off) red[tid] += red[tid + off];
        __syncthreads();
    }
    double sum = red[0];
#pragma unroll
    for (int j = 0; j < 4; ++j) {
        int p = tid * 4 + j;
        gk10[p] = __fmul_rn(10.0f, (float)(kv[j] / sum));
    }
}

// ---------------------------------------------------------------------------
// Main kernel: 4 waves per block, ONE WAVE PER PATCH. No __syncthreads.
// Histogram uses 32 replica columns with a rotating column assignment so no
// two lanes of a wave-op ever hit the same address beyond the free 2-way
// level, and consecutive pixels of a lane never reuse an address. All
// ds_add_f32 are fire-and-forget (no replay serialization).
// ---------------------------------------------------------------------------
__global__ __launch_bounds__(256) void orient_kernel(const float* __restrict__ x,
                                                     const float* __restrict__ gk10,
                                                     float* __restrict__ out) {
    const float PI_F    = 3.14159265358979323846f;   // 0x40490FDB
    const float TWOPI_F = 6.28318530717958647692f;   // 0x40C90FDB

    __shared__ __align__(16) float tile[WPB][NPIX];
    __shared__ __align__(16) float hist2[WPB][NB * RCOL];
    __shared__ int nflag[WPB];
    __shared__ int flagp[WPB][FCAP];

    const int tid = threadIdx.x;
    const int w = tid >> 6;          // wave id within block
    const int l = tid & 63;          // lane within wave
    const int patch = blockIdx.x * WPB + w;

    float* tw = tile[w];
    float* hw = hist2[w];

    // ---- Issue all global loads up front (patch + gaussian weights)
    const float4* src = reinterpret_cast<const float4*>(x + (size_t)patch * NPIX);
    float4 ld[4];    // lane's own 4 float4 groups (these ARE the "self" quads)
    float4 gkq[4];
#pragma unroll
    for (int k = 0; k < 4; ++k) ld[k] = src[k * 64 + l];
    const int r  = l >> 3;           // row within each 8-row band
    const int c0 = (l & 7) << 2;     // col 0,4,...,28
#pragma unroll
    for (int k = 0; k < 4; ++k)
        gkq[k] = *reinterpret_cast<const float4*>(&gk10[(k * 8 + r) * PS + c0]);

    // ---- Zero hist2 (1152 floats = 288 16B chunks) + flag counter
    {
        float4 z4 = make_float4(0.0f, 0.0f, 0.0f, 0.0f);
        float4* hz = reinterpret_cast<float4*>(hw);
#pragma unroll
        for (int jj = 0; jj < 4; ++jj) hz[jj * 64 + l] = z4;
        if (l < 32) hz[256 + l] = z4;
    }
    if (l == 0) nflag[w] = 0;

    // ---- Stage patch into LDS
    float4* dst = reinterpret_cast<float4*>(tw);
#pragma unroll
    for (int k = 0; k < 4; ++k) dst[k * 64 + l] = ld[k];
    asm volatile("s_waitcnt lgkmcnt(0)" ::: "memory");

    // ---- Hot loop: 16 pixels/lane
#pragma unroll
    for (int k = 0; k < 4; ++k) {
        const int row = k * 8 + r;
        const int rowOff = row << 5;
        const int upOff  = ((row == 0)  ? 0  : (row - 1)) << 5;   // replicate pad
        const int dnOff  = ((row == 31) ? 31 : (row + 1)) << 5;
        float4 up = *reinterpret_cast<const float4*>(&tw[upOff + c0]);
        float4 dn = *reinterpret_cast<const float4*>(&tw[dnOff + c0]);
        float lsc = tw[rowOff + ((c0 == 0) ? 0 : (c0 - 1))];
        float rsc = tw[rowOff + ((c0 + 4 > 31) ? 31 : (c0 + 4))];

        float sv[4]  = {ld[k].x, ld[k].y, ld[k].z, ld[k].w};
        float uv[4]  = {up.x, up.y, up.z, up.w};
        float dv[4]  = {dn.x, dn.y, dn.z, dn.w};
        float gk4[4] = {gkq[k].x, gkq[k].y, gkq[k].z, gkq[k].w};
        float lv[4]  = {lsc,   sv[0], sv[1], sv[2]};
        float rv[4]  = {sv[1], sv[2], sv[3], rsc};

#pragma unroll
        for (int j = 0; j < 4; ++j) {
            // Reference f32 op order for magnitude (no contraction):
            float gx = __fmul_rn(0.5f, __fsub_rn(lv[j], rv[j]));
            float gy = __fmul_rn(0.5f, __fsub_rn(uv[j], dv[j]));
            float s2 = __fadd_rn(__fadd_rn(__fmul_rn(gx, gx), __fmul_rn(gy, gy)), 1e-10f);
            float mag = __fmul_rn(__fsqrt_rn(s2), gk4[j]);

            // Fast atan2 directly in bin units: obig = (atan2+pi)*36/(2pi)
            float ax = fabsf(gx), ay = fabsf(gy);
            float mn = fminf(ax, ay), mx = fmaxf(ax, ay);
            float rr = mn * __builtin_amdgcn_rcpf(mx);   // ~1 ulp
            float t  = rr * rr;
            float u = 0.00282363896258175373077393f;     // SLEEF deg-17 odd minimax
            u = fmaf(u, t, -0.0159569028764963150024414f);
            u = fmaf(u, t,  0.0425049886107444763183594f);
            u = fmaf(u, t, -0.0748900920152664184570312f);
            u = fmaf(u, t,  0.106347933411598205566406f);
            u = fmaf(u, t, -0.142027363181114196777344f);
            u = fmaf(u, t,  0.199926957488059997558594f);
            u = fmaf(u, t, -0.333331018686294555664062f);
            float at = fmaf(rr * t, u, rr);              // atan(rr), [0, pi/4]
            float A  = at * 5.72957795130823208768f;     // -> bin units [0, 4.5]
            A = (mx > 0.0f) ? A : 0.0f;                  // atan2(0,0) = 0
            float q = (ay > ax) ? (9.0f - A) : A;
            q = (gx < 0.0f) ? (18.0f - q) : q;
            q = (gy < 0.0f) ? (0.0f - q) : q;
            float obig = q + 18.0f;                      // [0, 36]
            float bo0f = floorf(obig);
            float wo1  = __fsub_rn(obig, bo0f);

            // Boundary pixels: defer to exact f64 fixup (skip the add here)
            bool bad = (wo1 < 2e-5f) | (wo1 > 1.0f - 2e-5f);
            if (!bad) {
                int bo = (int)bo0f;
                if (bo >= NB) bo -= NB;
                float wo0 = __fmul_rn(__fsub_rn(1.0f, wo1), mag);
                // Rotating replica column: at each lockstep pixel step the 64
                // lanes cover the 32 columns exactly 2x (free level); a lane
                // never reuses a column across its 16 pixels.
                int col = (l + k * 4 + j) & (RCOL - 1);
                atomicAdd(&hw[bo * RCOL + col], wo0);    // ds_add_f32, no return
            } else {
                int idx = atomicAdd(&nflag[w], 1);
                if (idx < FCAP) flagp[w][idx] = rowOff + c0 + j;
            }
        }
    }
    asm volatile("s_waitcnt lgkmcnt(0)" ::: "memory");

    // ---- Exact f64 fixup for flagged pixels (~0.04 expected per patch)
    int nf = nflag[w];
    if (nf > FCAP) nf = FCAP;
    for (int s = l; s < nf; s += 64) {
        int p = flagp[w][s];
        int rr2 = p >> 5, cc = p & 31;
        float cl = tw[p - (cc > 0 ? 1 : 0)];
        float cr = tw[p + (cc < 31 ? 1 : 0)];
        float cu = tw[p - (rr2 > 0 ? 32 : 0)];
        float cd = tw[p + (rr2 < 31 ? 32 : 0)];
        float gx = __fmul_rn(0.5f, __fsub_rn(cl, cr));
        float gy = __fmul_rn(0.5f, __fsub_rn(cu, cd));
        float s2 = __fadd_rn(__fadd_rn(__fmul_rn(gx, gx), __fmul_rn(gy, gy)), 1e-10f);
        float mag = __fmul_rn(__fsqrt_rn(s2), gk10[p]);

        float ori  = (float)atan2((double)gy, (double)gx);  // correctly-rounded f32
        float obig = __fdiv_rn(__fmul_rn(36.0f, __fadd_rn(ori, PI_F)), TWOPI_F);
        float bo0f = floorf(obig);
        float wo1  = __fsub_rn(obig, bo0f);
        int bo = (int)bo0f;
        if (bo >= NB) bo -= NB;
        float wo0 = __fmul_rn(__fsub_rn(1.0f, wo1), mag);
        atomicAdd(&hw[bo * RCOL + (l & (RCOL - 1))], wo0);
    }
    asm volatile("s_waitcnt lgkmcnt(0)" ::: "memory");

    // ---- Reduce: lane b (<36) sums its 32 replica columns, scales by 1/1024
    float hval = 0.0f;
    if (l < NB) {
        const float4* hrow = reinterpret_cast<const float4*>(&hw[l * RCOL]);
        float tot = 0.0f;
#pragma unroll
        for (int k = 0; k < 8; ++k) {
            float4 a = hrow[k];
            tot += ((a.x + a.y) + (a.z + a.w));
        }
        hval = __fmul_rn(tot, 1.0f / 1024.0f);   // exact power-of-2 scale
    }

    // ---- Smoothing via lane shuffles (zero pad at both ends)
    float hm = __shfl_up(hval, 1, 64);
    if (l == 0) hm = 0.0f;
    float hp = __shfl_down(hval, 1, 64);         // lane 35 gets lane 36's 0
    float sm = 0.0f;
    if (l < NB) {
        sm = __fadd_rn(__fadd_rn(__fmul_rn(0.33f, hm), __fmul_rn(0.34f, hval)),
                       __fmul_rn(0.33f, hp));
    }

    // ---- First-wins argmax via packed-key butterfly (sm >= 0 always)
    unsigned long long key =
        (l < NB) ? ((((unsigned long long)__float_as_uint(sm)) << 6) |
                    (unsigned long long)(63 - l))
                 : 0ull;
#pragma unroll
    for (int off = 32; off > 0; off >>= 1) {
        unsigned long long o = __shfl_xor(key, off, 64);
        key = (o > key) ? o : key;
    }

    if (l == 0) {
        int bi = 63 - (int)(key & 63);
        float t2 = __fdiv_rn(__fmul_rn(TWOPI_F, (float)bi), 36.0f);
        out[patch] = __fsub_rn(PI_F, t2);
    }
}

extern "C" void kernel_launch(void* const* d_in, const int* in_sizes, int n_in,
                              void* d_out, int out_size, void* d_ws, size_t ws_size,
                              hipStream_t stream) {
    const float* x = (const float*)d_in[0];
    float* out = (float*)d_out;
    float* gk10 = (float*)d_ws;   // 1024 floats = 4 KB scratch

    const int B = in_sizes[0] / NPIX;

    gk_init_kernel<<<1, 256, 0, stream>>>(gk10);
    orient_kernel<<<B / WPB, 256, 0, stream>>>(x, gk10, out);
}

// Round 5
// 373.652 us; speedup vs baseline: 1.0407x; 1.0407x over previous
//
#include <hip/hip_runtime.h>

#define PS 32
#define NPIX (PS * PS)
#define NB 36
#define WPB 4      // waves (patches) per block
#define FCAP 64    // deferred-fixup list capacity per wave

// ---------------------------------------------------------------------------
// Init kernel: gk10[p] = float32(10 * CircularGaussKernel(32)) computed in f64,
// replicating numpy linspace + exp + normalize semantics, then cast to f32.
// ---------------------------------------------------------------------------
__global__ __launch_bounds__(256) void gk_init_kernel(float* __restrict__ gk10) {
    __shared__ double red[256];
    const int tid = threadIdx.x;
    const double delta = 32.0 / 31.0;       // numpy linspace step, f64
    const double sigma2 = 0.9 * 256.0;      // 0.9 * half^2, f64

    double kv[4];
    double s = 0.0;
#pragma unroll
    for (int j = 0; j < 4; ++j) {
        int p = tid * 4 + j;
        int r = p >> 5, c = p & 31;
        double xr = (r == 31) ? 16.0 : ((double)r * delta + (-16.0));
        double xc = (c == 31) ? 16.0 : ((double)c * delta + (-16.0));
        double d2 = xc * xc + xr * xr;
        kv[j] = exp(-d2 / sigma2);
        s += kv[j];
    }
    red[tid] = s;
    __syncthreads();
    for (int off = 128; off > 0; off >>= 1) {
        if (tid < off) red[tid] += red[tid + off];
        __syncthreads();
    }
    double sum = red[0];
#pragma unroll
    for (int j = 0; j < 4; ++j) {
        int p = tid * 4 + j;
        gk10[p] = __fmul_rn(10.0f, (float)(kv[j] / sum));
    }
}

// ---------------------------------------------------------------------------
// Main kernel: 4 waves per block, ONE WAVE PER PATCH. No __syncthreads.
// Two-stage structure to force cross-pixel ILP:
//   Stage A: all 16 pixels' gradients -> mag, signed ratio (S*rr), bin-offset
//            Cb, held in explicit register arrays (compiler cannot serialize).
//   Stage B: 16 INDEPENDENT atan polynomial chains -> obig = poly(S*rr)+Cb,
//            histogram adds. Quadrant logic folded into S (poly is exactly
//            odd) and additive Cb (exact small integers).
// ---------------------------------------------------------------------------
__global__ __launch_bounds__(256) void orient_kernel(const float* __restrict__ x,
                                                     const float* __restrict__ gk10,
                                                     float* __restrict__ out) {
    const float PI_F    = 3.14159265358979323846f;   // 0x40490FDB
    const float TWOPI_F = 6.28318530717958647692f;   // 0x40C90FDB

    __shared__ __align__(16) float tile[WPB][NPIX];
    __shared__ float hist[WPB][NB];
    __shared__ int   nflag[WPB];
    __shared__ int   flagp[WPB][FCAP];

    const int tid = threadIdx.x;
    const int w = tid >> 6;          // wave id within block
    const int l = tid & 63;          // lane within wave
    const int patch = blockIdx.x * WPB + w;

    float* tw = tile[w];
    float* hw = hist[w];

    // ---- Issue all global loads up front (patch + gaussian weights)
    const float4* src = reinterpret_cast<const float4*>(x + (size_t)patch * NPIX);
    float4 ld[4];    // lane's own 4 float4 groups (these ARE the "self" quads)
    float4 gkq[4];
#pragma unroll
    for (int k = 0; k < 4; ++k) ld[k] = src[k * 64 + l];
    const int r  = l >> 3;           // row within each 8-row band
    const int c0 = (l & 7) << 2;     // col 0,4,...,28
#pragma unroll
    for (int k = 0; k < 4; ++k)
        gkq[k] = *reinterpret_cast<const float4*>(&gk10[(k * 8 + r) * PS + c0]);

    // ---- Stage patch into LDS; init hist + flag counter
    float4* dst = reinterpret_cast<float4*>(tw);
#pragma unroll
    for (int k = 0; k < 4; ++k) dst[k * 64 + l] = ld[k];
    if (l < NB) hw[l] = 0.0f;
    if (l == 0) nflag[w] = 0;
    asm volatile("s_waitcnt lgkmcnt(0)" ::: "memory");

    // ---- Batched neighbor reads (issue together, one wait)
    float4 up[4], dn[4];
    float  lsc[4], rsc[4];
#pragma unroll
    for (int k = 0; k < 4; ++k) {
        const int row = k * 8 + r;
        const int rowOff = row << 5;
        const int upOff  = ((row == 0)  ? 0  : (row - 1)) << 5;   // replicate pad
        const int dnOff  = ((row == 31) ? 31 : (row + 1)) << 5;
        up[k]  = *reinterpret_cast<const float4*>(&tw[upOff + c0]);
        dn[k]  = *reinterpret_cast<const float4*>(&tw[dnOff + c0]);
        lsc[k] = tw[rowOff + ((c0 == 0) ? 0 : (c0 - 1))];
        rsc[k] = tw[rowOff + ((c0 + 4 > 31) ? 31 : (c0 + 4))];
    }

    // ======================= STAGE A =======================
    // Per pixel i: magv[i], rrs[i] = S * min/max ratio (sign-folded),
    // cbv[i] = additive bin offset. All exact-integer Cb in {0,9,18,27,36}.
    float rrs[16], magv[16], cbv[16];
#pragma unroll
    for (int k = 0; k < 4; ++k) {
        float sv[4]  = {ld[k].x, ld[k].y, ld[k].z, ld[k].w};
        float uv[4]  = {up[k].x, up[k].y, up[k].z, up[k].w};
        float dv[4]  = {dn[k].x, dn[k].y, dn[k].z, dn[k].w};
        float gk4[4] = {gkq[k].x, gkq[k].y, gkq[k].z, gkq[k].w};
        float lv[4]  = {lsc[k], sv[0], sv[1], sv[2]};
        float rv[4]  = {sv[1],  sv[2], sv[3], rsc[k]};
#pragma unroll
        for (int j = 0; j < 4; ++j) {
            const int i = k * 4 + j;
            // Reference f32 op order for magnitude (no contraction):
            float gx = __fmul_rn(0.5f, __fsub_rn(lv[j], rv[j]));
            float gy = __fmul_rn(0.5f, __fsub_rn(uv[j], dv[j]));
            float s2 = __fadd_rn(__fadd_rn(__fmul_rn(gx, gx), __fmul_rn(gy, gy)), 1e-10f);
            magv[i] = __fmul_rn(__fsqrt_rn(s2), gk4[j]);

            float ax = fabsf(gx), ay = fabsf(gy);
            float mn = fminf(ax, ay), mx = fmaxf(ax, ay);
            float rr = mn * __builtin_amdgcn_rcpf(mx);   // ~1 ulp
            rr = (mx > 0.0f) ? rr : 0.0f;                // atan2(0,0) = 0

            // Quadrant folding: obig = S*atan_bins(rr) + Cb
            //   base (gx>0,gy>0,ax>=ay): S=+1, Cb=18
            //   ay>ax : atan -> 9-atan   => S=-S_pre... chain below
            //   gx<0  : q -> 18-q        => S=-S, Cb=54-Cb
            //   gy<0  : q -> -q          => S=-S, Cb=36-Cb
            bool c1 = ay > ax;
            bool c2 = gx < 0.0f;
            bool c3 = gy < 0.0f;
            float S  = c1 ? -1.0f : 1.0f;
            float Cb = c1 ? 27.0f : 18.0f;
            S  = c2 ? -S : S;
            Cb = c2 ? __fsub_rn(54.0f, Cb) : Cb;   // exact small ints
            S  = c3 ? -S : S;
            Cb = c3 ? __fsub_rn(36.0f, Cb) : Cb;
            rrs[i] = rr * S;                       // exact (S = +/-1)
            cbv[i] = Cb;
        }
    }

    // ======================= STAGE B =======================
    // 16 independent chains: atan poly (exactly odd in rrs) -> obig -> bin.
    const float BINSCALE = 5.72957795130823208768f;   // 18/pi (bins per radian)
#pragma unroll
    for (int i = 0; i < 16; ++i) {
        float rr = rrs[i];
        float t  = rr * rr;
        float u = 0.00282363896258175373077393f;      // SLEEF deg-17 odd minimax
        u = fmaf(u, t, -0.0159569028764963150024414f);
        u = fmaf(u, t,  0.0425049886107444763183594f);
        u = fmaf(u, t, -0.0748900920152664184570312f);
        u = fmaf(u, t,  0.106347933411598205566406f);
        u = fmaf(u, t, -0.142027363181114196777344f);
        u = fmaf(u, t,  0.199926957488059997558594f);
        u = fmaf(u, t, -0.333331018686294555664062f);
        float at   = fmaf(rr * t, u, rr);             // odd: at(-x) = -at(x)
        float obig = fmaf(at, BINSCALE, cbv[i]);      // [0, 36]
        float bo0f = floorf(obig);
        float wo1  = __fsub_rn(obig, bo0f);

        bool bad = (wo1 < 2e-5f) | (wo1 > 1.0f - 2e-5f);
        if (!bad) {
            int bo = (int)bo0f;
            if (bo >= NB) bo -= NB;
            float wo0 = __fmul_rn(__fsub_rn(1.0f, wo1), magv[i]);
            atomicAdd(&hw[bo], wo0);
        } else {
            int idx = atomicAdd(&nflag[w], 1);
            const int row = (i >> 2) * 8 + r;
            if (idx < FCAP) flagp[w][idx] = (row << 5) + c0 + (i & 3);
        }
    }
    asm volatile("s_waitcnt lgkmcnt(0)" ::: "memory");

    // ---- Exact f64 fixup for flagged pixels (~0.04 expected per patch)
    int nf = nflag[w];
    if (nf > FCAP) nf = FCAP;
    for (int s = l; s < nf; s += 64) {
        int p = flagp[w][s];
        int rr2 = p >> 5, cc = p & 31;
        float cl = tw[p - (cc > 0 ? 1 : 0)];
        float cr = tw[p + (cc < 31 ? 1 : 0)];
        float cu = tw[p - (rr2 > 0 ? 32 : 0)];
        float cd = tw[p + (rr2 < 31 ? 32 : 0)];
        float gx = __fmul_rn(0.5f, __fsub_rn(cl, cr));
        float gy = __fmul_rn(0.5f, __fsub_rn(cu, cd));
        float s2 = __fadd_rn(__fadd_rn(__fmul_rn(gx, gx), __fmul_rn(gy, gy)), 1e-10f);
        float mag = __fmul_rn(__fsqrt_rn(s2), gk10[p]);

        float ori  = (float)atan2((double)gy, (double)gx);  // correctly-rounded f32
        float obig = __fdiv_rn(__fmul_rn(36.0f, __fadd_rn(ori, PI_F)), TWOPI_F);
        float bo0f = floorf(obig);
        float wo1  = __fsub_rn(obig, bo0f);
        int bo = (int)bo0f;
        if (bo >= NB) bo -= NB;
        float wo0 = __fmul_rn(__fsub_rn(1.0f, wo1), mag);
        atomicAdd(&hw[bo], wo0);
    }
    asm volatile("s_waitcnt lgkmcnt(0)" ::: "memory");

    // ---- Smoothing (lanes 0..35): sm = 0.33*h[i-1] + 0.34*h[i] + 0.33*h[i+1]
    float sm = 0.0f;
    if (l < NB) {
        const float inv = 1.0f / 1024.0f;  // exact power of 2
        float hm = (l > 0)      ? __fmul_rn(hw[l - 1], inv) : 0.0f;
        float h0 =                __fmul_rn(hw[l],     inv);
        float hp = (l < NB - 1) ? __fmul_rn(hw[l + 1], inv) : 0.0f;
        sm = __fadd_rn(__fadd_rn(__fmul_rn(0.33f, hm), __fmul_rn(0.34f, h0)),
                       __fmul_rn(0.33f, hp));
    }

    // ---- First-wins argmax via packed-key butterfly (sm >= 0 always)
    unsigned long long key =
        (l < NB) ? ((((unsigned long long)__float_as_uint(sm)) << 6) |
                    (unsigned long long)(63 - l))
                 : 0ull;
#pragma unroll
    for (int off = 32; off > 0; off >>= 1) {
        unsigned long long o = __shfl_xor(key, off, 64);
        key = (o > key) ? o : key;
    }

    if (l == 0) {
        int bi = 63 - (int)(key & 63);
        float t2 = __fdiv_rn(__fmul_rn(TWOPI_F, (float)bi), 36.0f);
        out[patch] = __fsub_rn(PI_F, t2);
    }
}

extern "C" void kernel_launch(void* const* d_in, const int* in_sizes, int n_in,
                              void* d_out, int out_size, void* d_ws, size_t ws_size,
                              hipStream_t stream) {
    const float* x = (const float*)d_in[0];
    float* out = (float*)d_out;
    float* gk10 = (float*)d_ws;   // 1024 floats = 4 KB scratch

    const int B = in_sizes[0] / NPIX;

    gk_init_kernel<<<1, 256, 0, stream>>>(gk10);
    orient_kernel<<<B / WPB, 256, 0, stream>>>(x, gk10, out);
}